// Round 1
// baseline (3183.692 us; speedup 1.0000x reference)
//
#include <hip/hip_runtime.h>
#include <cstddef>

#define C 128

// Fused: for j in {0,1,2}: h_j = x @ W[j] + b[j]
// j==0 -> out[:, 0:128] (stride 384), j==1 -> h1, j==2 -> h2 (stride 128)
__global__ __launch_bounds__(256) void gemm3(
    const float* __restrict__ x, const float* __restrict__ W,
    const float* __restrict__ bias, float* __restrict__ out,
    float* __restrict__ h1, float* __restrict__ h2, int N) {
  __shared__ float xs[32][C];
  const int j = blockIdx.y;
  const int row0 = blockIdx.x * 32;
  const int tid = threadIdx.x;
  // stage 32-row x tile in LDS (16 KB)
  for (int i = tid; i < 32 * C; i += 256) {
    int r = i >> 7, c = i & 127;
    int gr = row0 + r;
    xs[r][c] = (gr < N) ? x[(size_t)gr * C + c] : 0.0f;
  }
  __syncthreads();
  const float* __restrict__ Wj = W + (size_t)j * C * C;
  const int tc = tid & 31;   // col base: cols tc, tc+32, tc+64, tc+96
  const int tr = tid >> 5;   // row base: rows tr, tr+8, tr+16, tr+24
  float acc[4][4];
#pragma unroll
  for (int m = 0; m < 4; ++m)
#pragma unroll
    for (int q = 0; q < 4; ++q) acc[m][q] = 0.0f;

#pragma unroll 4
  for (int k = 0; k < C; ++k) {
    const float w0 = Wj[k * C + tc];
    const float w1 = Wj[k * C + tc + 32];
    const float w2 = Wj[k * C + tc + 64];
    const float w3 = Wj[k * C + tc + 96];
    float xv[4];
#pragma unroll
    for (int m = 0; m < 4; ++m) xv[m] = xs[tr + 8 * m][k];
#pragma unroll
    for (int m = 0; m < 4; ++m) {
      acc[m][0] += xv[m] * w0;
      acc[m][1] += xv[m] * w1;
      acc[m][2] += xv[m] * w2;
      acc[m][3] += xv[m] * w3;
    }
  }

  const float b0 = bias[j * C + tc];
  const float b1 = bias[j * C + tc + 32];
  const float b2 = bias[j * C + tc + 64];
  const float b3 = bias[j * C + tc + 96];

#pragma unroll
  for (int m = 0; m < 4; ++m) {
    const int gr = row0 + tr + 8 * m;
    if (gr >= N) continue;
    if (j == 0) {
      float* dst = out + (size_t)gr * 384;
      dst[tc]      = acc[m][0] + b0;
      dst[tc + 32] = acc[m][1] + b1;
      dst[tc + 64] = acc[m][2] + b2;
      dst[tc + 96] = acc[m][3] + b3;
    } else {
      float* dst = ((j == 1) ? h1 : h2) + (size_t)gr * C;
      dst[tc]      = acc[m][0] + b0;
      dst[tc + 32] = acc[m][1] + b1;
      dst[tc + 64] = acc[m][2] + b2;
      dst[tc + 96] = acc[m][3] + b3;
    }
  }
}

// out[row[e], :] += val[e] * h[col[e], :]  via atomics.
// 32 threads per edge, each thread does 4 channels (float4 gather).
__global__ __launch_bounds__(256) void spmm_atomic(
    const float* __restrict__ h, const float* __restrict__ val,
    const int* __restrict__ row, const int* __restrict__ col,
    float* __restrict__ out, int E, int ostride) {
  const int e = blockIdx.x * 8 + (threadIdx.x >> 5);
  if (e >= E) return;
  const int c = (threadIdx.x & 31) * 4;
  const float v = val[e];
  const int cl = col[e];
  const int r = row[e];
  const float4 hv = *reinterpret_cast<const float4*>(h + (size_t)cl * C + c);
  float* dst = out + (size_t)r * ostride + c;
  atomicAdd(dst + 0, v * hv.x);
  atomicAdd(dst + 1, v * hv.y);
  atomicAdd(dst + 2, v * hv.z);
  atomicAdd(dst + 3, v * hv.w);
}

extern "C" void kernel_launch(void* const* d_in, const int* in_sizes, int n_in,
                              void* d_out, int out_size, void* d_ws, size_t ws_size,
                              hipStream_t stream) {
  const float* x  = (const float*)d_in[0];
  const float* W  = (const float*)d_in[1];
  const float* b  = (const float*)d_in[2];
  const float* ev = (const float*)d_in[3];
  const int*   er = (const int*)d_in[4];
  const int*   ec = (const int*)d_in[5];
  const int N = in_sizes[0] / C;
  const int E = in_sizes[3];
  float* out = (float*)d_out;

  const size_t NB = (size_t)N * C;  // elements per [N,128] buffer
  float* h1 = (float*)d_ws;         // x @ W[1] + b[1]
  float* h2 = h1 + NB;              // x @ W[2] + b[2]
  float* t  = h2 + NB;              // adj_t @ h2

  // zero-init atomic destinations
  hipMemsetAsync(d_out, 0, (size_t)N * 3 * C * sizeof(float), stream);
  hipMemsetAsync(t, 0, NB * sizeof(float), stream);

  dim3 ggrid((N + 31) / 32, 3);
  gemm3<<<ggrid, 256, 0, stream>>>(x, W, b, out, h1, h2, N);

  const int sblocks = (E + 7) / 8;
  // hop1: out[:,128:256] = A_t @ h1
  spmm_atomic<<<sblocks, 256, 0, stream>>>(h1, ev, er, ec, out + C, E, 3 * C);
  // hop2: t = A_t @ h2 ; out[:,256:384] = A_t @ t
  spmm_atomic<<<sblocks, 256, 0, stream>>>(h2, ev, er, ec, t, E, C);
  spmm_atomic<<<sblocks, 256, 0, stream>>>(t, ev, er, ec, out + 2 * C, E, 3 * C);
}

// Round 2
// 405.527 us; speedup vs baseline: 7.8508x; 7.8508x over previous
//
#include <hip/hip_runtime.h>
#include <cstddef>

#define C 128

// Fused: for j in {0,1,2}: h_j = x @ W[j] + b[j]
__global__ __launch_bounds__(256) void gemm3(
    const float* __restrict__ x, const float* __restrict__ W,
    const float* __restrict__ bias, float* __restrict__ out,
    float* __restrict__ h1, float* __restrict__ h2, int N) {
  __shared__ float xs[32][C];
  const int j = blockIdx.y;
  const int row0 = blockIdx.x * 32;
  const int tid = threadIdx.x;
  for (int i = tid; i < 32 * C; i += 256) {
    int r = i >> 7, c = i & 127;
    int gr = row0 + r;
    xs[r][c] = (gr < N) ? x[(size_t)gr * C + c] : 0.0f;
  }
  __syncthreads();
  const float* __restrict__ Wj = W + (size_t)j * C * C;
  const int tc = tid & 31;
  const int tr = tid >> 5;
  float acc[4][4];
#pragma unroll
  for (int m = 0; m < 4; ++m)
#pragma unroll
    for (int q = 0; q < 4; ++q) acc[m][q] = 0.0f;

#pragma unroll 4
  for (int k = 0; k < C; ++k) {
    const float w0 = Wj[k * C + tc];
    const float w1 = Wj[k * C + tc + 32];
    const float w2 = Wj[k * C + tc + 64];
    const float w3 = Wj[k * C + tc + 96];
    float xv[4];
#pragma unroll
    for (int m = 0; m < 4; ++m) xv[m] = xs[tr + 8 * m][k];
#pragma unroll
    for (int m = 0; m < 4; ++m) {
      acc[m][0] += xv[m] * w0;
      acc[m][1] += xv[m] * w1;
      acc[m][2] += xv[m] * w2;
      acc[m][3] += xv[m] * w3;
    }
  }

  const float b0 = bias[j * C + tc];
  const float b1 = bias[j * C + tc + 32];
  const float b2 = bias[j * C + tc + 64];
  const float b3 = bias[j * C + tc + 96];

#pragma unroll
  for (int m = 0; m < 4; ++m) {
    const int gr = row0 + tr + 8 * m;
    if (gr >= N) continue;
    float* dst = (j == 0) ? (out + (size_t)gr * 384)
                          : (((j == 1) ? h1 : h2) + (size_t)gr * C);
    dst[tc]      = acc[m][0] + b0;
    dst[tc + 32] = acc[m][1] + b1;
    dst[tc + 64] = acc[m][2] + b2;
    dst[tc + 96] = acc[m][3] + b3;
  }
}

// --- CSR build ---------------------------------------------------------
__global__ __launch_bounds__(256) void hist_rows(
    const int* __restrict__ row, int* __restrict__ cnt, int E) {
  int i = blockIdx.x * 256 + threadIdx.x;
  int stride = gridDim.x * 256;
  for (; i < E; i += stride) atomicAdd(&cnt[row[i]], 1);
}

// single-block exclusive scan: row_ptr[i] = sum_{k<i} cnt[k]; cursor := row_ptr
__global__ __launch_bounds__(1024) void scan_rows(
    const int* __restrict__ cnt, int* __restrict__ row_ptr,
    int* __restrict__ cursor, int N) {
  __shared__ int buf[1024];
  __shared__ int carry_s;
  const int tid = threadIdx.x;
  if (tid == 0) carry_s = 0;
  __syncthreads();
  for (int base = 0; base < N; base += 1024) {
    const int i = base + tid;
    const int v = (i < N) ? cnt[i] : 0;
    buf[tid] = v;
    __syncthreads();
#pragma unroll
    for (int off = 1; off < 1024; off <<= 1) {
      int t = (tid >= off) ? buf[tid - off] : 0;
      __syncthreads();
      buf[tid] += t;
      __syncthreads();
    }
    const int carry = carry_s;
    const int excl = buf[tid] - v + carry;
    if (i < N) { row_ptr[i] = excl; cursor[i] = excl; }
    const int total = buf[1023];
    __syncthreads();
    if (tid == 0) carry_s = carry + total;
    __syncthreads();
  }
  if (tid == 0) row_ptr[N] = carry_s;
}

__global__ __launch_bounds__(256) void scatter_edges(
    const int* __restrict__ row, const int* __restrict__ col,
    const float* __restrict__ val, int* __restrict__ cursor,
    int* __restrict__ scol, float* __restrict__ sval, int E) {
  int i = blockIdx.x * 256 + threadIdx.x;
  int stride = gridDim.x * 256;
  for (; i < E; i += stride) {
    int r = row[i];
    int pos = atomicAdd(&cursor[r], 1);
    scol[pos] = col[i];
    sval[pos] = val[i];
  }
}

// --- SpMM: one 64-lane wave per row, float2 per lane -------------------
__global__ __launch_bounds__(256) void spmm_csr(
    const float* __restrict__ h, const int* __restrict__ rp,
    const int* __restrict__ scol, const float* __restrict__ sval,
    float* __restrict__ out, int N, int ostride) {
  const int r = blockIdx.x * 4 + (threadIdx.x >> 6);
  if (r >= N) return;
  const int c = (threadIdx.x & 63) * 2;
  const int s = rp[r];
  const int e = rp[r + 1];
  float2 acc = make_float2(0.0f, 0.0f);
  int i = s;
  for (; i + 1 < e; i += 2) {
    const int c0 = scol[i], c1 = scol[i + 1];
    const float v0 = sval[i], v1 = sval[i + 1];
    const float2 h0 = *reinterpret_cast<const float2*>(h + (size_t)c0 * C + c);
    const float2 h1 = *reinterpret_cast<const float2*>(h + (size_t)c1 * C + c);
    acc.x += v0 * h0.x + v1 * h1.x;
    acc.y += v0 * h0.y + v1 * h1.y;
  }
  if (i < e) {
    const int c0 = scol[i];
    const float v0 = sval[i];
    const float2 h0 = *reinterpret_cast<const float2*>(h + (size_t)c0 * C + c);
    acc.x += v0 * h0.x;
    acc.y += v0 * h0.y;
  }
  *reinterpret_cast<float2*>(out + (size_t)r * ostride + c) = acc;
}

extern "C" void kernel_launch(void* const* d_in, const int* in_sizes, int n_in,
                              void* d_out, int out_size, void* d_ws, size_t ws_size,
                              hipStream_t stream) {
  const float* x  = (const float*)d_in[0];
  const float* W  = (const float*)d_in[1];
  const float* b  = (const float*)d_in[2];
  const float* ev = (const float*)d_in[3];
  const int*   er = (const int*)d_in[4];
  const int*   ec = (const int*)d_in[5];
  const int N = in_sizes[0] / C;
  const int E = in_sizes[3];
  float* out = (float*)d_out;

  const size_t NB = (size_t)N * C;
  char* ws = (char*)d_ws;
  float* h1      = (float*)ws;                 ws += NB * sizeof(float);
  float* h2      = (float*)ws;                 ws += NB * sizeof(float);
  int*   row_ptr = (int*)ws;                   ws += (size_t)(N + 1) * sizeof(int);
  int*   cursor  = (int*)ws;                   ws += (size_t)N * sizeof(int);
  int*   scol    = (int*)ws;                   ws += (size_t)E * sizeof(int);
  float* sval    = (float*)ws;
  float* t = h1;  // reuse: h1 is dead after hop1's spmm

  // CSR build (uses cursor as the count buffer first)
  hipMemsetAsync(cursor, 0, (size_t)N * sizeof(int), stream);
  const int eblocks = (E + 255) / 256 < 2048 ? (E + 255) / 256 : 2048;
  hist_rows<<<eblocks, 256, 0, stream>>>(er, cursor, E);
  scan_rows<<<1, 1024, 0, stream>>>(cursor, row_ptr, cursor, N);
  scatter_edges<<<eblocks, 256, 0, stream>>>(er, ec, ev, cursor, scol, sval, E);

  // 3 fused linears
  dim3 ggrid((N + 31) / 32, 3);
  gemm3<<<ggrid, 256, 0, stream>>>(x, W, b, out, h1, h2, N);

  // SpMM passes (atomic-free)
  const int sblocks = (N + 3) / 4;
  spmm_csr<<<sblocks, 256, 0, stream>>>(h1, row_ptr, scol, sval, out + C, N, 3 * C);
  spmm_csr<<<sblocks, 256, 0, stream>>>(h2, row_ptr, scol, sval, t, N, C);
  spmm_csr<<<sblocks, 256, 0, stream>>>(t, row_ptr, scol, sval, out + 2 * C, N, 3 * C);
}

// Round 3
// 295.998 us; speedup vs baseline: 10.7558x; 1.3700x over previous
//
#include <hip/hip_runtime.h>
#include <cstddef>

#define C 128
#define TM 64

// ---- fused 3x linear: h_j = x @ W[j] + b[j] ---------------------------
// 64 rows x 128 cols per block; thread = 8 rows x 4 cols (32 acc)
__global__ __launch_bounds__(256) void gemm3(
    const float* __restrict__ x, const float* __restrict__ W,
    const float* __restrict__ bias, float* __restrict__ out,
    float* __restrict__ h1, float* __restrict__ h2, int N) {
  __shared__ float xs[TM][C + 4];  // +4 keeps float4 alignment per row
  const int j = blockIdx.y;
  const int row0 = blockIdx.x * TM;
  const int tid = threadIdx.x;

  // stage 64x128 x-tile (float4 loads)
#pragma unroll
  for (int it = 0; it < 8; ++it) {
    int flat = it * 256 + tid;        // 0..2047
    int r = flat >> 5;                // 0..63
    int kq = (flat & 31) << 2;        // 0,4,...,124
    int gr = row0 + r;
    float4 v = make_float4(0.f, 0.f, 0.f, 0.f);
    if (gr < N) v = *reinterpret_cast<const float4*>(x + (size_t)gr * C + kq);
    *reinterpret_cast<float4*>(&xs[r][kq]) = v;
  }
  __syncthreads();

  const float* __restrict__ Wj = W + (size_t)j * C * C;
  const int tc4 = (tid & 31) << 2;   // col base (float4)
  const int r0 = (tid >> 5) << 3;    // row base (8 rows)

  float acc[8][4];
#pragma unroll
  for (int m = 0; m < 8; ++m)
#pragma unroll
    for (int q = 0; q < 4; ++q) acc[m][q] = 0.0f;

  const float* wp = Wj + tc4;
  float4 w0 = *reinterpret_cast<const float4*>(wp);
  float4 w1 = *reinterpret_cast<const float4*>(wp + C);
#pragma unroll 2
  for (int k = 0; k < C; k += 2) {
    float4 nw0 = w0, nw1 = w1;
    if (k + 2 < C) {
      nw0 = *reinterpret_cast<const float4*>(wp + (size_t)(k + 2) * C);
      nw1 = *reinterpret_cast<const float4*>(wp + (size_t)(k + 3) * C);
    }
#pragma unroll
    for (int m = 0; m < 8; ++m) {
      float2 xv = *reinterpret_cast<const float2*>(&xs[r0 + m][k]);
      acc[m][0] += xv.x * w0.x; acc[m][1] += xv.x * w0.y;
      acc[m][2] += xv.x * w0.z; acc[m][3] += xv.x * w0.w;
      acc[m][0] += xv.y * w1.x; acc[m][1] += xv.y * w1.y;
      acc[m][2] += xv.y * w1.z; acc[m][3] += xv.y * w1.w;
    }
    w0 = nw0; w1 = nw1;
  }

  const float4 bv = *reinterpret_cast<const float4*>(bias + (size_t)j * C + tc4);
  float* base = (j == 0) ? out : ((j == 1) ? h1 : h2);
  const int stride = (j == 0) ? 384 : 128;
#pragma unroll
  for (int m = 0; m < 8; ++m) {
    const int gr = row0 + r0 + m;
    if (gr >= N) continue;
    float4 o;
    o.x = acc[m][0] + bv.x; o.y = acc[m][1] + bv.y;
    o.z = acc[m][2] + bv.z; o.w = acc[m][3] + bv.w;
    *reinterpret_cast<float4*>(base + (size_t)gr * stride + tc4) = o;
  }
}

// ---- CSR build --------------------------------------------------------
__global__ __launch_bounds__(256) void hist_rows(
    const int* __restrict__ row, int* __restrict__ cnt, int E) {
  int i = blockIdx.x * 256 + threadIdx.x;
  int stride = gridDim.x * 256;
  for (; i < E; i += stride) atomicAdd(&cnt[row[i]], 1);
}

// per-1024-block scan: part[i] = local exclusive prefix; bsum[b] = block total
__global__ __launch_bounds__(1024) void scan_local(
    const int* __restrict__ cnt, int* __restrict__ part,
    int* __restrict__ bsum, int N) {
  __shared__ int wsum[16];
  const int tid = threadIdx.x;
  const int i = blockIdx.x * 1024 + tid;
  const int v = (i < N) ? cnt[i] : 0;
  const int lane = tid & 63, w = tid >> 6;
  int s = v;
#pragma unroll
  for (int off = 1; off < 64; off <<= 1) {
    int t = __shfl_up(s, off, 64);
    if (lane >= off) s += t;
  }
  if (lane == 63) wsum[w] = s;
  __syncthreads();
  if (tid < 16) {
    int ws = wsum[tid];
#pragma unroll
    for (int off = 1; off < 16; off <<= 1) {
      int t = __shfl_up(ws, off, 16);
      if (tid >= off) ws += t;
    }
    wsum[tid] = ws;  // inclusive wave-prefix
  }
  __syncthreads();
  const int woff = w ? wsum[w - 1] : 0;
  if (i < N) part[i] = woff + s - v;
  if (tid == 0) bsum[blockIdx.x] = wsum[15];
}

// 1 block, 64 threads: carry[b] = exclusive prefix of bsum; row_ptr[N] = total
__global__ __launch_bounds__(64) void scan_carry(
    const int* __restrict__ bsum, int* __restrict__ carry,
    int* __restrict__ row_ptr, int nb, int N) {
  const int tid = threadIdx.x;
  const int v = (tid < nb) ? bsum[tid] : 0;
  int s = v;
#pragma unroll
  for (int off = 1; off < 64; off <<= 1) {
    int t = __shfl_up(s, off, 64);
    if (tid >= off) s += t;
  }
  if (tid < nb) carry[tid] = s - v;
  if (tid == 63) row_ptr[N] = s;
}

__global__ __launch_bounds__(1024) void scan_apply(
    int* __restrict__ part, const int* __restrict__ carry,
    int* __restrict__ cursor, int N) {
  const int i = blockIdx.x * 1024 + threadIdx.x;
  if (i < N) {
    const int v = part[i] + carry[blockIdx.x];
    part[i] = v;
    cursor[i] = v;
  }
}

__global__ __launch_bounds__(256) void scatter_edges(
    const int* __restrict__ row, const int* __restrict__ col,
    const float* __restrict__ val, int* __restrict__ cursor,
    int2* __restrict__ ep, int E) {
  int i = blockIdx.x * 256 + threadIdx.x;
  int stride = gridDim.x * 256;
  for (; i < E; i += stride) {
    int r = row[i];
    int pos = atomicAdd(&cursor[r], 1);
    ep[pos] = make_int2(col[i], __float_as_int(val[i]));
  }
}

// ---- SpMM: 32 lanes x float4 per row, 8 rows per block ----------------
__global__ __launch_bounds__(256) void spmm_csr(
    const float* __restrict__ h, const int* __restrict__ rp,
    const int2* __restrict__ ep, float* __restrict__ outp,
    int N, int ostride) {
  const int r = blockIdx.x * 8 + (threadIdx.x >> 5);
  if (r >= N) return;
  const int cg = (threadIdx.x & 31) << 2;
  const int s = rp[r];
  const int e = rp[r + 1];
  float4 a0 = make_float4(0.f, 0.f, 0.f, 0.f);
  float4 a1 = make_float4(0.f, 0.f, 0.f, 0.f);
  int i = s;
  for (; i + 1 < e; i += 2) {
    const int2 e0 = ep[i];
    const int2 e1 = ep[i + 1];
    const float v0 = __int_as_float(e0.y);
    const float v1 = __int_as_float(e1.y);
    const float4 g0 = *reinterpret_cast<const float4*>(h + (size_t)e0.x * C + cg);
    const float4 g1 = *reinterpret_cast<const float4*>(h + (size_t)e1.x * C + cg);
    a0.x += v0 * g0.x; a0.y += v0 * g0.y; a0.z += v0 * g0.z; a0.w += v0 * g0.w;
    a1.x += v1 * g1.x; a1.y += v1 * g1.y; a1.z += v1 * g1.z; a1.w += v1 * g1.w;
  }
  if (i < e) {
    const int2 e0 = ep[i];
    const float v0 = __int_as_float(e0.y);
    const float4 g0 = *reinterpret_cast<const float4*>(h + (size_t)e0.x * C + cg);
    a0.x += v0 * g0.x; a0.y += v0 * g0.y; a0.z += v0 * g0.z; a0.w += v0 * g0.w;
  }
  float4 res;
  res.x = a0.x + a1.x; res.y = a0.y + a1.y;
  res.z = a0.z + a1.z; res.w = a0.w + a1.w;
  *reinterpret_cast<float4*>(outp + (size_t)r * ostride + cg) = res;
}

extern "C" void kernel_launch(void* const* d_in, const int* in_sizes, int n_in,
                              void* d_out, int out_size, void* d_ws, size_t ws_size,
                              hipStream_t stream) {
  const float* x  = (const float*)d_in[0];
  const float* W  = (const float*)d_in[1];
  const float* b  = (const float*)d_in[2];
  const float* ev = (const float*)d_in[3];
  const int*   er = (const int*)d_in[4];
  const int*   ec = (const int*)d_in[5];
  const int N = in_sizes[0] / C;
  const int E = in_sizes[3];
  float* out = (float*)d_out;

  const size_t NB = (size_t)N * C;
  char* ws = (char*)d_ws;
  float* h1      = (float*)ws;  ws += NB * sizeof(float);
  float* h2      = (float*)ws;  ws += NB * sizeof(float);
  int*   row_ptr = (int*)ws;    ws += (size_t)(N + 1) * sizeof(int);
  int*   cursor  = (int*)ws;    ws += (size_t)N * sizeof(int);
  int*   bsum    = (int*)ws;    ws += 64 * sizeof(int);
  int*   carry   = (int*)ws;    ws += 64 * sizeof(int);
  int2*  ep      = (int2*)ws;
  float* t = h1;  // h1 dead after hop-1 spmm (stream-serialized)

  const int nb = (N + 1023) / 1024;

  // CSR build (cursor doubles as the count buffer)
  hipMemsetAsync(cursor, 0, (size_t)N * sizeof(int), stream);
  const int eb0 = (E + 255) / 256;
  const int eblocks = eb0 < 2048 ? eb0 : 2048;
  hist_rows<<<eblocks, 256, 0, stream>>>(er, cursor, E);
  scan_local<<<nb, 1024, 0, stream>>>(cursor, row_ptr, bsum, N);
  scan_carry<<<1, 64, 0, stream>>>(bsum, carry, row_ptr, nb, N);
  scan_apply<<<nb, 1024, 0, stream>>>(row_ptr, carry, cursor, N);
  scatter_edges<<<eblocks, 256, 0, stream>>>(er, ec, ev, cursor, ep, E);

  // fused linears
  dim3 ggrid((N + TM - 1) / TM, 3);
  gemm3<<<ggrid, 256, 0, stream>>>(x, W, b, out, h1, h2, N);

  // SpMM passes
  const int sblocks = (N + 7) / 8;
  spmm_csr<<<sblocks, 256, 0, stream>>>(h1, row_ptr, ep, out + C, N, 3 * C);
  spmm_csr<<<sblocks, 256, 0, stream>>>(h2, row_ptr, ep, t, N, C);
  spmm_csr<<<sblocks, 256, 0, stream>>>(t, row_ptr, ep, out + 2 * C, N, 3 * C);
}